// Round 2
// baseline (139.806 us; speedup 1.0000x reference)
//
#include <hip/hip_runtime.h>
#include <hip/hip_bf16.h>

#define NN 6144
#define NF 512
#define NH 256
#define JSPLIT 4
#define JSLICE (NN / JSPLIT)   // 1536
#define BR 32                  // K3 rows per block
#define NT (JSLICE / 64)       // 24 j-tiles per block

typedef __attribute__((ext_vector_type(4))) float f32x4;
typedef __attribute__((ext_vector_type(8))) short s16x8;
typedef __attribute__((ext_vector_type(4))) short s16x4;

__device__ __forceinline__ ushort f2bf(float f) {
    unsigned u = __builtin_bit_cast(unsigned, f);
    u += 0x7fffu + ((u >> 16) & 1u);   // RNE (finite values only)
    return (ushort)(u >> 16);
}

__device__ __forceinline__ float wave_red_add(float v) {
#pragma unroll
    for (int s = 32; s; s >>= 1) v += __shfl_xor(v, s);
    return v;
}

// ---------------- K0: W (512x256 f32, k-major) -> WbT (256x512 bf16, n-major)
__global__ __launch_bounds__(256) void k0_prep(const float* __restrict__ W,
                                               ushort* __restrict__ WbT) {
    int idx = blockIdx.x * 256 + threadIdx.x;   // 0..131071
    int k = idx >> 8, n = idx & 255;
    WbT[n * NF + k] = f2bf(W[idx]);
}

// ---------------- K1: Wh = x @ W  (6144x512 * 512x256), MFMA bf16
__global__ __launch_bounds__(256) void k1_gemm(const float* __restrict__ x,
                                               const ushort* __restrict__ WbT,
                                               float* __restrict__ Wh,
                                               ushort* __restrict__ WhbT) {
    __shared__ ushort Asm[128 * 64];   // [row][k] swizzled
    __shared__ ushort Bsm[64 * 64];    // [n][k] swizzled
    const int t = threadIdx.x, lane = t & 63, wid = t >> 6;
    const int rb = blockIdx.x;   // 0..47 (128 rows)
    const int cb = blockIdx.y;   // 0..3  (64 cols)
    const int wrow = wid >> 1, wcol = wid & 1;
    f32x4 acc[4][2];
#pragma unroll
    for (int i = 0; i < 4; ++i)
#pragma unroll
        for (int j = 0; j < 2; ++j) acc[i][j] = (f32x4){0.f, 0.f, 0.f, 0.f};

    for (int kt = 0; kt < NF; kt += 64) {
        __syncthreads();
#pragma unroll
        for (int c = 0; c < 4; ++c) {
            int idx = c * 256 + t;           // 0..1023
            int row = idx >> 3, k8 = idx & 7;
            const float* src = x + (rb * 128 + row) * NF + kt + k8 * 8;
            float4 lo = *reinterpret_cast<const float4*>(src);
            float4 hi = *reinterpret_cast<const float4*>(src + 4);
            union { s16x8 v; ushort u[8]; } pk;
            pk.u[0] = f2bf(lo.x); pk.u[1] = f2bf(lo.y);
            pk.u[2] = f2bf(lo.z); pk.u[3] = f2bf(lo.w);
            pk.u[4] = f2bf(hi.x); pk.u[5] = f2bf(hi.y);
            pk.u[6] = f2bf(hi.z); pk.u[7] = f2bf(hi.w);
            int byte = (row * 128 + k8 * 16) ^ ((row & 7) << 4);
            *reinterpret_cast<s16x8*>((char*)Asm + byte) = pk.v;
        }
#pragma unroll
        for (int c = 0; c < 2; ++c) {
            int idx = c * 256 + t;           // 0..511
            int row = idx >> 3, k8 = idx & 7;
            s16x8 v = *reinterpret_cast<const s16x8*>(WbT + (cb * 64 + row) * NF + kt + k8 * 8);
            int byte = (row * 128 + k8 * 16) ^ ((row & 7) << 4);
            *reinterpret_cast<s16x8*>((char*)Bsm + byte) = v;
        }
        __syncthreads();
#pragma unroll
        for (int kk = 0; kk < 64; kk += 32) {
            const int kbyte = (kk + ((lane >> 4) * 8)) * 2;
            s16x8 af[4], bfr[2];
#pragma unroll
            for (int fi = 0; fi < 4; ++fi) {
                int row = wrow * 64 + fi * 16 + (lane & 15);
                int byte = (row * 128 + kbyte) ^ ((row & 7) << 4);
                af[fi] = *reinterpret_cast<const s16x8*>((char*)Asm + byte);
            }
#pragma unroll
            for (int fj = 0; fj < 2; ++fj) {
                int nn = wcol * 32 + fj * 16 + (lane & 15);
                int byte = (nn * 128 + kbyte) ^ ((nn & 7) << 4);
                bfr[fj] = *reinterpret_cast<const s16x8*>((char*)Bsm + byte);
            }
#pragma unroll
            for (int fi = 0; fi < 4; ++fi)
#pragma unroll
                for (int fj = 0; fj < 2; ++fj)
                    acc[fi][fj] = __builtin_amdgcn_mfma_f32_16x16x32_bf16(
                        af[fi], bfr[fj], acc[fi][fj], 0, 0, 0);
        }
    }
#pragma unroll
    for (int fi = 0; fi < 4; ++fi)
#pragma unroll
        for (int fj = 0; fj < 2; ++fj) {
            int grow0 = rb * 128 + wrow * 64 + fi * 16 + (lane >> 4) * 4;
            int gcol = cb * 64 + wcol * 32 + fj * 16 + (lane & 15);
            union { s16x4 v; ushort u[4]; } pk;
#pragma unroll
            for (int r = 0; r < 4; ++r) {
                float v = acc[fi][fj][r];
                Wh[(grow0 + r) * NH + gcol] = v;
                pk.u[r] = f2bf(v);
            }
            *reinterpret_cast<s16x4*>(WhbT + gcol * NN + grow0) = pk.v;
        }
}

// ---------------- K2: f1 = Wh@a1, f2 = Wh@a2 (one wave per row)
__global__ __launch_bounds__(256) void k2_f12(const float* __restrict__ Wh,
                                              const float* __restrict__ a,
                                              float* __restrict__ f1,
                                              float* __restrict__ f2) {
    int row = blockIdx.x * 4 + (threadIdx.x >> 6);
    int lane = threadIdx.x & 63;
    float4 wv = *reinterpret_cast<const float4*>(Wh + row * NH + lane * 4);
    float4 a1 = *reinterpret_cast<const float4*>(a + lane * 4);
    float4 a2 = *reinterpret_cast<const float4*>(a + NH + lane * 4);
    float d1 = wv.x * a1.x + wv.y * a1.y + wv.z * a1.z + wv.w * a1.w;
    float d2 = wv.x * a2.x + wv.y * a2.y + wv.z * a2.z + wv.w * a2.w;
    d1 = wave_red_add(d1);
    d2 = wave_red_add(d2);
    if (lane == 0) { f1[row] = d1; f2[row] = d2; }
}

// ---------------- K3: fused flash-style attention (partial over j-slice)
// 32 rows x 256 cols per block; grid (192, JSPLIT) = 768 blocks.
// Pipelined: adj/f2 regs prefetched 1 tile ahead; double-buffered LDS w tile;
// one barrier per tile.
__global__ __launch_bounds__(256) void k3_attn(const int* __restrict__ adj,
                                               const ushort* __restrict__ WhbT,
                                               const float* __restrict__ f1,
                                               const float* __restrict__ f2,
                                               float* __restrict__ hpart,
                                               float* __restrict__ Zpart) {
    __shared__ ushort wlds[2][BR * 64];   // w tiles, [row][j] bf16, XOR-swizzled
    const int t = threadIdx.x, lane = t & 63, wid = t >> 6;
    const int rb = blockIdx.x;        // 0..191 (32 rows each)
    const int js = blockIdx.y;        // 0..JSPLIT-1
    const int row0 = rb * BR;
    const int j0 = js * JSLICE;

    const int wrow = t >> 3;          // 0..31: this thread's w-gen row
    const int cbase = (t & 7) * 8;    // 8 cols per thread
    const float f1v = f1[row0 + wrow];
    const int* aptr = adj + (row0 + wrow) * NN + j0 + cbase;
    const float* f2p = f2 + j0 + cbase;
    float zsum = 0.f;

    f32x4 acc[2][4];
#pragma unroll
    for (int i = 0; i < 2; ++i)
#pragma unroll
        for (int j = 0; j < 4; ++j) acc[i][j] = (f32x4){0.f, 0.f, 0.f, 0.f};

    // prologue: load tile 0 operands
    int4 av0 = *reinterpret_cast<const int4*>(aptr);
    int4 av1 = *reinterpret_cast<const int4*>(aptr + 4);
    f32x4 gv0 = *reinterpret_cast<const f32x4*>(f2p);
    f32x4 gv1 = *reinterpret_cast<const f32x4*>(f2p + 4);

    for (int jt = 0; jt < NT; ++jt) {
        // --- w = adj ? exp(leakyrelu(f1+f2)) : 0  (8 values/thread, from regs)
        union { s16x8 v; ushort u[8]; } pk;
        {
            float e, w;
            const int ai[8] = {av0.x, av0.y, av0.z, av0.w, av1.x, av1.y, av1.z, av1.w};
            float gg[8] = {gv0[0], gv0[1], gv0[2], gv0[3], gv1[0], gv1[1], gv1[2], gv1[3]};
#pragma unroll
            for (int q = 0; q < 8; ++q) {
                e = f1v + gg[q];
                e = e > 0.f ? e : 0.2f * e;
                w = (ai[q] != 0) ? __expf(e) : 0.f;
                zsum += w;
                pk.u[q] = f2bf(w);
            }
        }
        {
            int byte = (wrow * 128 + cbase * 2) ^ ((wrow & 7) << 4);
            *reinterpret_cast<s16x8*>((char*)&wlds[jt & 1][0] + byte) = pk.v;
        }
        // --- prefetch next tile's adj/f2 into regs (latency hides under MFMA)
        if (jt + 1 < NT) {
            const int* ap = aptr + (jt + 1) * 64;
            const float* fp = f2p + (jt + 1) * 64;
            av0 = *reinterpret_cast<const int4*>(ap);
            av1 = *reinterpret_cast<const int4*>(ap + 4);
            gv0 = *reinterpret_cast<const f32x4*>(fp);
            gv1 = *reinterpret_cast<const f32x4*>(fp + 4);
        }
        __syncthreads();
        // --- MFMA: acc(32x64 per wave) += w(32x64) @ Whb(64x64cols)
        const char* buf = (const char*)&wlds[jt & 1][0];
#pragma unroll
        for (int kk = 0; kk < 64; kk += 32) {
            const int kbyte = (kk + (lane >> 4) * 8) * 2;
            s16x8 af[2];
#pragma unroll
            for (int fi = 0; fi < 2; ++fi) {
                int row = fi * 16 + (lane & 15);
                int byte = (row * 128 + kbyte) ^ ((row & 7) << 4);
                af[fi] = *reinterpret_cast<const s16x8*>(buf + byte);
            }
            const int jg = j0 + jt * 64 + kk + (lane >> 4) * 8;
#pragma unroll
            for (int fj = 0; fj < 4; ++fj) {
                int col = wid * 64 + fj * 16 + (lane & 15);
                s16x8 bv = *reinterpret_cast<const s16x8*>(WhbT + col * NN + jg);
#pragma unroll
                for (int fi = 0; fi < 2; ++fi)
                    acc[fi][fj] = __builtin_amdgcn_mfma_f32_16x16x32_bf16(
                        af[fi], bv, acc[fi][fj], 0, 0, 0);
            }
        }
    }
    // --- write partial h and Z
#pragma unroll
    for (int fi = 0; fi < 2; ++fi)
#pragma unroll
        for (int fj = 0; fj < 4; ++fj) {
            int prow0 = row0 + fi * 16 + (lane >> 4) * 4;
            int pcol = wid * 64 + fj * 16 + (lane & 15);
#pragma unroll
            for (int r = 0; r < 4; ++r)
                hpart[(js * NN + prow0 + r) * NH + pcol] = acc[fi][fj][r];
        }
    zsum += __shfl_xor(zsum, 1);
    zsum += __shfl_xor(zsum, 2);
    zsum += __shfl_xor(zsum, 4);
    if ((t & 7) == 0) Zpart[js * NN + row0 + wrow] = zsum;
}

// ---------------- K4: combine j-split partials, normalize, elu, two dots
__global__ __launch_bounds__(256) void k4_reduce(const float* __restrict__ hpart,
                                                 const float* __restrict__ Zpart,
                                                 const float* __restrict__ fcW,
                                                 float* __restrict__ out1,
                                                 float* __restrict__ p) {
    int row = blockIdx.x * 4 + (threadIdx.x >> 6);
    int lane = threadIdx.x & 63;
    f32x4 s = (f32x4){0.f, 0.f, 0.f, 0.f};
    float Z = 0.f;
#pragma unroll
    for (int js = 0; js < JSPLIT; ++js) {
        f32x4 hv = *reinterpret_cast<const f32x4*>(hpart + (js * NN + row) * NH + lane * 4);
        s += hv;
        Z += Zpart[js * NN + row];
    }
    float inv = 1.f / Z;
    float h[4];
#pragma unroll
    for (int r = 0; r < 4; ++r) {
        float v = s[r] * inv;
        h[r] = v > 0.f ? v : expm1f(v);   // elu, alpha=1
    }
    float4 fc1 = *reinterpret_cast<const float4*>(fcW + lane * 4);
    float4 fc2 = *reinterpret_cast<const float4*>(fcW + NH + lane * 4);
    float d1 = h[0] * fc1.x + h[1] * fc1.y + h[2] * fc1.z + h[3] * fc1.w;
    float d2 = h[0] * fc2.x + h[1] * fc2.y + h[2] * fc2.z + h[3] * fc2.w;
    d1 = wave_red_add(d1);
    d2 = wave_red_add(d2);
    if (lane == 0) { out1[row] = d1; p[row] = d2; }
}

// ---------------- K5: c = sum(p) + fcb; out = out1 + c (single block, deterministic)
__global__ __launch_bounds__(256) void k5_final(const float* __restrict__ out1,
                                                const float* __restrict__ p,
                                                const float* __restrict__ fcb,
                                                float* __restrict__ out) {
    __shared__ float red[256];
    int t = threadIdx.x;
    float s = 0.f;
    for (int i = t; i < NN; i += 256) s += p[i];
    red[t] = s;
    __syncthreads();
    for (int h = 128; h; h >>= 1) {
        if (t < h) red[t] += red[t + h];
        __syncthreads();
    }
    float c = red[0] + fcb[0];
    for (int i = t; i < NN; i += 256) out[i] = out1[i] + c;
}

extern "C" void kernel_launch(void* const* d_in, const int* in_sizes, int n_in,
                              void* d_out, int out_size, void* d_ws, size_t ws_size,
                              hipStream_t stream) {
    const float* x   = (const float*)d_in[0];
    const int*   adj = (const int*)d_in[1];
    const float* W   = (const float*)d_in[2];
    const float* a   = (const float*)d_in[3];
    const float* fcW = (const float*)d_in[4];
    const float* fcb = (const float*)d_in[5];
    float* out = (float*)d_out;
    char* ws = (char*)d_ws;

    constexpr size_t oWbT   = 0;                           // 256*512*2   = 262144
    constexpr size_t oWhbT  = oWbT + 262144;               // 256*6144*2  = 3145728
    constexpr size_t oWh    = oWhbT + 3145728;             // 6144*256*4  = 6291456
    constexpr size_t oF1    = oWh + 6291456;               // 24576
    constexpr size_t oF2    = oF1 + 24576;                 // 24576
    constexpr size_t oHp    = oF2 + 24576;                 // 4*6144*256*4 = 25165824
    constexpr size_t oZp    = oHp + 25165824;              // 98304
    constexpr size_t oOut1  = oZp + 98304;                 // 24576
    constexpr size_t oP     = oOut1 + 24576;               // 24576

    ushort* WbT  = (ushort*)(ws + oWbT);
    ushort* WhbT = (ushort*)(ws + oWhbT);
    float*  Wh   = (float*)(ws + oWh);
    float*  f1   = (float*)(ws + oF1);
    float*  f2   = (float*)(ws + oF2);
    float*  hp   = (float*)(ws + oHp);
    float*  Zp   = (float*)(ws + oZp);
    float*  out1 = (float*)(ws + oOut1);
    float*  p    = (float*)(ws + oP);

    k0_prep<<<dim3(512), dim3(256), 0, stream>>>(W, WbT);
    k1_gemm<<<dim3(48, 4), dim3(256), 0, stream>>>(x, WbT, Wh, WhbT);
    k2_f12<<<dim3(1536), dim3(256), 0, stream>>>(Wh, a, f1, f2);
    k3_attn<<<dim3(NN / BR, JSPLIT), dim3(256), 0, stream>>>(adj, WhbT, f1, f2, hp, Zp);
    k4_reduce<<<dim3(1536), dim3(256), 0, stream>>>(hp, Zp, fcW, out1, p);
    k5_final<<<dim3(1), dim3(256), 0, stream>>>(out1, p, fcb, out);
}

// Round 3
// 96.775 us; speedup vs baseline: 1.4446x; 1.4446x over previous
//
#include <hip/hip_runtime.h>
#include <hip/hip_bf16.h>

#define NN 6144
#define NF 512
#define NH 256
#define JSPLIT 4
#define JSLICE (NN / JSPLIT)   // 1536
#define BR 32                  // K3 rows per block
#define NT (JSLICE / 64)       // 24 j-tiles per block

typedef __attribute__((ext_vector_type(4))) float f32x4;
typedef __attribute__((ext_vector_type(8))) short s16x8;
typedef __attribute__((ext_vector_type(4))) short s16x4;

__device__ __forceinline__ ushort f2bf(float f) {
    unsigned u = __builtin_bit_cast(unsigned, f);
    u += 0x7fffu + ((u >> 16) & 1u);   // RNE (finite values only)
    return (ushort)(u >> 16);
}

__device__ __forceinline__ float wave_red_add(float v) {
#pragma unroll
    for (int s = 32; s; s >>= 1) v += __shfl_xor(v, s);
    return v;
}

// ---------------- K0: W (512x256 f32, k-major) -> WbT (256x512 bf16, n-major)
__global__ __launch_bounds__(256) void k0_prep(const float* __restrict__ W,
                                               ushort* __restrict__ WbT) {
    int idx = blockIdx.x * 256 + threadIdx.x;   // 0..131071
    int k = idx >> 8, n = idx & 255;
    WbT[n * NF + k] = f2bf(W[idx]);
}

// ---------------- K1: Wh = x @ W  (6144x512 * 512x256), MFMA bf16
__global__ __launch_bounds__(256) void k1_gemm(const float* __restrict__ x,
                                               const ushort* __restrict__ WbT,
                                               float* __restrict__ Wh,
                                               ushort* __restrict__ WhbT) {
    __shared__ ushort Asm[128 * 64];   // [row][k] swizzled
    __shared__ ushort Bsm[64 * 64];    // [n][k] swizzled
    const int t = threadIdx.x, lane = t & 63, wid = t >> 6;
    const int rb = blockIdx.x;   // 0..47 (128 rows)
    const int cb = blockIdx.y;   // 0..3  (64 cols)
    const int wrow = wid >> 1, wcol = wid & 1;
    f32x4 acc[4][2];
#pragma unroll
    for (int i = 0; i < 4; ++i)
#pragma unroll
        for (int j = 0; j < 2; ++j) acc[i][j] = (f32x4){0.f, 0.f, 0.f, 0.f};

    for (int kt = 0; kt < NF; kt += 64) {
        __syncthreads();
#pragma unroll
        for (int c = 0; c < 4; ++c) {
            int idx = c * 256 + t;           // 0..1023
            int row = idx >> 3, k8 = idx & 7;
            const float* src = x + (rb * 128 + row) * NF + kt + k8 * 8;
            float4 lo = *reinterpret_cast<const float4*>(src);
            float4 hi = *reinterpret_cast<const float4*>(src + 4);
            union { s16x8 v; ushort u[8]; } pk;
            pk.u[0] = f2bf(lo.x); pk.u[1] = f2bf(lo.y);
            pk.u[2] = f2bf(lo.z); pk.u[3] = f2bf(lo.w);
            pk.u[4] = f2bf(hi.x); pk.u[5] = f2bf(hi.y);
            pk.u[6] = f2bf(hi.z); pk.u[7] = f2bf(hi.w);
            int byte = (row * 128 + k8 * 16) ^ ((row & 7) << 4);
            *reinterpret_cast<s16x8*>((char*)Asm + byte) = pk.v;
        }
#pragma unroll
        for (int c = 0; c < 2; ++c) {
            int idx = c * 256 + t;           // 0..511
            int row = idx >> 3, k8 = idx & 7;
            s16x8 v = *reinterpret_cast<const s16x8*>(WbT + (cb * 64 + row) * NF + kt + k8 * 8);
            int byte = (row * 128 + k8 * 16) ^ ((row & 7) << 4);
            *reinterpret_cast<s16x8*>((char*)Bsm + byte) = v;
        }
        __syncthreads();
#pragma unroll
        for (int kk = 0; kk < 64; kk += 32) {
            const int kbyte = (kk + ((lane >> 4) * 8)) * 2;
            s16x8 af[4], bfr[2];
#pragma unroll
            for (int fi = 0; fi < 4; ++fi) {
                int row = wrow * 64 + fi * 16 + (lane & 15);
                int byte = (row * 128 + kbyte) ^ ((row & 7) << 4);
                af[fi] = *reinterpret_cast<const s16x8*>((char*)Asm + byte);
            }
#pragma unroll
            for (int fj = 0; fj < 2; ++fj) {
                int nn = wcol * 32 + fj * 16 + (lane & 15);
                int byte = (nn * 128 + kbyte) ^ ((nn & 7) << 4);
                bfr[fj] = *reinterpret_cast<const s16x8*>((char*)Bsm + byte);
            }
#pragma unroll
            for (int fi = 0; fi < 4; ++fi)
#pragma unroll
                for (int fj = 0; fj < 2; ++fj)
                    acc[fi][fj] = __builtin_amdgcn_mfma_f32_16x16x32_bf16(
                        af[fi], bfr[fj], acc[fi][fj], 0, 0, 0);
        }
    }
#pragma unroll
    for (int fi = 0; fi < 4; ++fi)
#pragma unroll
        for (int fj = 0; fj < 2; ++fj) {
            int grow0 = rb * 128 + wrow * 64 + fi * 16 + (lane >> 4) * 4;
            int gcol = cb * 64 + wcol * 32 + fj * 16 + (lane & 15);
            union { s16x4 v; ushort u[4]; } pk;
#pragma unroll
            for (int r = 0; r < 4; ++r) {
                float v = acc[fi][fj][r];
                Wh[(grow0 + r) * NH + gcol] = v;
                pk.u[r] = f2bf(v);
            }
            *reinterpret_cast<s16x4*>(WhbT + gcol * NN + grow0) = pk.v;
        }
}

// ---------------- K2: f1 = Wh@a1, f2 = Wh@a2 (one wave per row)
__global__ __launch_bounds__(256) void k2_f12(const float* __restrict__ Wh,
                                              const float* __restrict__ a,
                                              float* __restrict__ f1,
                                              float* __restrict__ f2) {
    int row = blockIdx.x * 4 + (threadIdx.x >> 6);
    int lane = threadIdx.x & 63;
    float4 wv = *reinterpret_cast<const float4*>(Wh + row * NH + lane * 4);
    float4 a1 = *reinterpret_cast<const float4*>(a + lane * 4);
    float4 a2 = *reinterpret_cast<const float4*>(a + NH + lane * 4);
    float d1 = wv.x * a1.x + wv.y * a1.y + wv.z * a1.z + wv.w * a1.w;
    float d2 = wv.x * a2.x + wv.y * a2.y + wv.z * a2.z + wv.w * a2.w;
    d1 = wave_red_add(d1);
    d2 = wave_red_add(d2);
    if (lane == 0) { f1[row] = d1; f2[row] = d2; }
}

// ---------------- K3: fused flash-style attention (partial over j-slice)
// 32 rows x 256 cols per block; grid (192, JSPLIT) = 768 blocks.
// B tile (256 cols x 64 j, 32KB) staged into LDS via global_load_lds with
// pre-swizzled source (linear LDS dest); all MFMA operands from LDS.
// barrier2 is a raw s_barrier with lgkmcnt-only drain so the adj/f2 HBM
// prefetch stays in flight across it.
__global__ __launch_bounds__(256) void k3_attn(const int* __restrict__ adj,
                                               const ushort* __restrict__ WhbT,
                                               const float* __restrict__ f1,
                                               const float* __restrict__ f2,
                                               float* __restrict__ hpart,
                                               float* __restrict__ Zpart) {
    __shared__ ushort Bsm[256 * 64];      // [col][j] bf16, XOR-swizzled, 32KB
    __shared__ ushort wlds[2][BR * 64];   // w tiles, [row][j] bf16, swizzled, 8KB
    const int t = threadIdx.x, lane = t & 63, wid = t >> 6;
    const int rb = blockIdx.x;        // 0..191 (32 rows each)
    const int js = blockIdx.y;        // 0..JSPLIT-1
    const int row0 = rb * BR;
    const int j0 = js * JSLICE;

    const int wrow = t >> 3;          // 0..31: this thread's w-gen row
    const int cbase = (t & 7) * 8;    // 8 cols per thread
    const float f1v = f1[row0 + wrow];
    const int* aptr = adj + (row0 + wrow) * NN + j0 + cbase;
    const float* f2p = f2 + j0 + cbase;
    float zsum = 0.f;

    // staging helper: one B tile (cols 0..255, j = jg..jg+63) -> Bsm
    // lane l of wave wid, round r: col = r*32 + wid*8 + (l>>3); linear chunk
    // q' = l&7 holds global chunk q'^(col&7)  (self-inverse swizzle).
    auto stage = [&](int jg) {
#pragma unroll
        for (int r = 0; r < 8; ++r) {
            int colbase = r * 32 + wid * 8;
            int col = colbase + (lane >> 3);
            int q = (lane & 7) ^ (col & 7);
            const ushort* src = WhbT + col * NN + jg + q * 8;
            __builtin_amdgcn_global_load_lds(
                (const __attribute__((address_space(1))) unsigned int*)src,
                (__attribute__((address_space(3))) unsigned int*)(Bsm + colbase * 64),
                16, 0, 0);
        }
    };

    f32x4 acc[2][4];
#pragma unroll
    for (int i = 0; i < 2; ++i)
#pragma unroll
        for (int j = 0; j < 4; ++j) acc[i][j] = (f32x4){0.f, 0.f, 0.f, 0.f};

    // prologue: stage B tile 0, load adj/f2 regs for tile 0
    stage(j0);
    int4 av0 = *reinterpret_cast<const int4*>(aptr);
    int4 av1 = *reinterpret_cast<const int4*>(aptr + 4);
    f32x4 gv0 = *reinterpret_cast<const f32x4*>(f2p);
    f32x4 gv1 = *reinterpret_cast<const f32x4*>(f2p + 4);

    for (int jt = 0; jt < NT; ++jt) {
        // --- w = adj ? exp(leakyrelu(f1+f2)) : 0  (8 values/thread, from regs)
        union { s16x8 v; ushort u[8]; } pk;
        {
            const int ai[8] = {av0.x, av0.y, av0.z, av0.w, av1.x, av1.y, av1.z, av1.w};
            const float gg[8] = {gv0[0], gv0[1], gv0[2], gv0[3], gv1[0], gv1[1], gv1[2], gv1[3]};
#pragma unroll
            for (int q = 0; q < 8; ++q) {
                float e = f1v + gg[q];
                e = e > 0.f ? e : 0.2f * e;
                float w = (ai[q] != 0) ? __expf(e) : 0.f;
                zsum += w;
                pk.u[q] = f2bf(w);
            }
        }
        {
            int byte = (wrow * 128 + cbase * 2) ^ ((wrow & 7) << 4);
            *reinterpret_cast<s16x8*>((char*)&wlds[jt & 1][0] + byte) = pk.v;
        }
        // barrier1: needs B-stage(jt) + wlds writes complete (full drain ok —
        // no adj prefetch is in flight here).
        __syncthreads();
        // --- issue next tile's adj/f2 prefetch NOW: full MFMA+stage+wgen
        // window before first use; NOT drained by barrier2 (lgkmcnt-only).
        if (jt + 1 < NT) {
            const int* ap = aptr + (jt + 1) * 64;
            const float* fp = f2p + (jt + 1) * 64;
            av0 = *reinterpret_cast<const int4*>(ap);
            av1 = *reinterpret_cast<const int4*>(ap + 4);
            gv0 = *reinterpret_cast<const f32x4*>(fp);
            gv1 = *reinterpret_cast<const f32x4*>(fp + 4);
        }
        __builtin_amdgcn_sched_barrier(0);   // pin prefetch issue before MFMA phase
        // --- MFMA: acc(32x64 per wave) += w(32x64) @ B(64x64cols), all from LDS
        const char* buf = (const char*)&wlds[jt & 1][0];
#pragma unroll
        for (int kk = 0; kk < 64; kk += 32) {
            const int kbyte = (kk + (lane >> 4) * 8) * 2;
            s16x8 af[2];
#pragma unroll
            for (int fi = 0; fi < 2; ++fi) {
                int row = fi * 16 + (lane & 15);
                int byte = (row * 128 + kbyte) ^ ((row & 7) << 4);
                af[fi] = *reinterpret_cast<const s16x8*>(buf + byte);
            }
#pragma unroll
            for (int fj = 0; fj < 4; ++fj) {
                int col = wid * 64 + fj * 16 + (lane & 15);
                int bbyte = (col * 128 + kbyte) ^ ((col & 7) << 4);
                s16x8 bv = *reinterpret_cast<const s16x8*>((const char*)Bsm + bbyte);
#pragma unroll
                for (int fi = 0; fi < 2; ++fi)
                    acc[fi][fj] = __builtin_amdgcn_mfma_f32_16x16x32_bf16(
                        af[fi], bv, acc[fi][fj], 0, 0, 0);
            }
        }
        // barrier2: protect Bsm for restaging. LDS reads must be done
        // (lgkmcnt(0)); adj/f2 global loads stay in flight (no vmcnt drain).
        asm volatile("s_waitcnt lgkmcnt(0)" ::: "memory");
        __builtin_amdgcn_sched_barrier(0);
        __builtin_amdgcn_s_barrier();
        if (jt + 1 < NT) stage(j0 + (jt + 1) * 64);
    }
    // --- write partial h and Z
#pragma unroll
    for (int fi = 0; fi < 2; ++fi)
#pragma unroll
        for (int fj = 0; fj < 4; ++fj) {
            int prow0 = row0 + fi * 16 + (lane >> 4) * 4;
            int pcol = wid * 64 + fj * 16 + (lane & 15);
#pragma unroll
            for (int r = 0; r < 4; ++r)
                hpart[(js * NN + prow0 + r) * NH + pcol] = acc[fi][fj][r];
        }
    zsum += __shfl_xor(zsum, 1);
    zsum += __shfl_xor(zsum, 2);
    zsum += __shfl_xor(zsum, 4);
    if ((t & 7) == 0) Zpart[js * NN + row0 + wrow] = zsum;
}

// ---------------- K4: combine j-split partials, normalize, elu, two dots
__global__ __launch_bounds__(256) void k4_reduce(const float* __restrict__ hpart,
                                                 const float* __restrict__ Zpart,
                                                 const float* __restrict__ fcW,
                                                 float* __restrict__ out1,
                                                 float* __restrict__ p) {
    int row = blockIdx.x * 4 + (threadIdx.x >> 6);
    int lane = threadIdx.x & 63;
    f32x4 s = (f32x4){0.f, 0.f, 0.f, 0.f};
    float Z = 0.f;
#pragma unroll
    for (int js = 0; js < JSPLIT; ++js) {
        f32x4 hv = *reinterpret_cast<const f32x4*>(hpart + (js * NN + row) * NH + lane * 4);
        s += hv;
        Z += Zpart[js * NN + row];
    }
    float inv = 1.f / Z;
    float h[4];
#pragma unroll
    for (int r = 0; r < 4; ++r) {
        float v = s[r] * inv;
        h[r] = v > 0.f ? v : expm1f(v);   // elu, alpha=1
    }
    float4 fc1 = *reinterpret_cast<const float4*>(fcW + lane * 4);
    float4 fc2 = *reinterpret_cast<const float4*>(fcW + NH + lane * 4);
    float d1 = h[0] * fc1.x + h[1] * fc1.y + h[2] * fc1.z + h[3] * fc1.w;
    float d2 = h[0] * fc2.x + h[1] * fc2.y + h[2] * fc2.z + h[3] * fc2.w;
    d1 = wave_red_add(d1);
    d2 = wave_red_add(d2);
    if (lane == 0) { out1[row] = d1; p[row] = d2; }
}

// ---------------- K5: c = sum(p) + fcb; out = out1 + c (single block, deterministic)
__global__ __launch_bounds__(256) void k5_final(const float* __restrict__ out1,
                                                const float* __restrict__ p,
                                                const float* __restrict__ fcb,
                                                float* __restrict__ out) {
    __shared__ float red[256];
    int t = threadIdx.x;
    float s = 0.f;
    for (int i = t; i < NN; i += 256) s += p[i];
    red[t] = s;
    __syncthreads();
    for (int h = 128; h; h >>= 1) {
        if (t < h) red[t] += red[t + h];
        __syncthreads();
    }
    float c = red[0] + fcb[0];
    for (int i = t; i < NN; i += 256) out[i] = out1[i] + c;
}

extern "C" void kernel_launch(void* const* d_in, const int* in_sizes, int n_in,
                              void* d_out, int out_size, void* d_ws, size_t ws_size,
                              hipStream_t stream) {
    const float* x   = (const float*)d_in[0];
    const int*   adj = (const int*)d_in[1];
    const float* W   = (const float*)d_in[2];
    const float* a   = (const float*)d_in[3];
    const float* fcW = (const float*)d_in[4];
    const float* fcb = (const float*)d_in[5];
    float* out = (float*)d_out;
    char* ws = (char*)d_ws;

    constexpr size_t oWbT   = 0;                           // 256*512*2   = 262144
    constexpr size_t oWhbT  = oWbT + 262144;               // 256*6144*2  = 3145728
    constexpr size_t oWh    = oWhbT + 3145728;             // 6144*256*4  = 6291456
    constexpr size_t oF1    = oWh + 6291456;               // 24576
    constexpr size_t oF2    = oF1 + 24576;                 // 24576
    constexpr size_t oHp    = oF2 + 24576;                 // 4*6144*256*4 = 25165824
    constexpr size_t oZp    = oHp + 25165824;              // 98304
    constexpr size_t oOut1  = oZp + 98304;                 // 24576
    constexpr size_t oP     = oOut1 + 24576;               // 24576

    ushort* WbT  = (ushort*)(ws + oWbT);
    ushort* WhbT = (ushort*)(ws + oWhbT);
    float*  Wh   = (float*)(ws + oWh);
    float*  f1   = (float*)(ws + oF1);
    float*  f2   = (float*)(ws + oF2);
    float*  hp   = (float*)(ws + oHp);
    float*  Zp   = (float*)(ws + oZp);
    float*  out1 = (float*)(ws + oOut1);
    float*  p    = (float*)(ws + oP);

    k0_prep<<<dim3(512), dim3(256), 0, stream>>>(W, WbT);
    k1_gemm<<<dim3(48, 4), dim3(256), 0, stream>>>(x, WbT, Wh, WhbT);
    k2_f12<<<dim3(1536), dim3(256), 0, stream>>>(Wh, a, f1, f2);
    k3_attn<<<dim3(NN / BR, JSPLIT), dim3(256), 0, stream>>>(adj, WhbT, f1, f2, hp, Zp);
    k4_reduce<<<dim3(1536), dim3(256), 0, stream>>>(hp, Zp, fcW, out1, p);
    k5_final<<<dim3(1), dim3(256), 0, stream>>>(out1, p, fcb, out);
}